// Round 8
// baseline (174.821 us; speedup 1.0000x reference)
//
#include <hip/hip_runtime.h>

#define T_LEN 200
#define F_IN  32
#define TC    8                 // timesteps per chunk; 200 = 25 * 8
#define NCH   (T_LEN / TC)
#define NB    8                 // batches per block
#define PSTR  264               // P stride per batch (dwords), 16B-aligned
#define ZSTR  204               // z stride per batch (dwords), 16B-aligned rows

#define QP(a,b,c,d) ((a)|((b)<<2)|((c)<<4)|((d)<<6))
#define DPP_HM 0x141            // row_half_mirror: lane^7 within each 8-group
#define EX2(v) __builtin_amdgcn_exp2f(v)
#define RCP(v) __builtin_amdgcn_rcpf(v)

typedef short  bf16x8  __attribute__((ext_vector_type(8)));
typedef float  floatx4 __attribute__((ext_vector_type(4)));
typedef float  floatx2 __attribute__((ext_vector_type(2)));

template <int CTRL>
__device__ __forceinline__ float dppf(float v) {
    return __int_as_float(__builtin_amdgcn_update_dpp(
        0, __float_as_int(v), CTRL, 0xF, 0xF, true));
}
// fused butterfly stages: dst = dpp(src) + src, one VALU instr each
// (s_nop 1 guards the VALU-write -> DPP-read hazard; asm is opaque to the
//  compiler's hazard recognizer)
__device__ __forceinline__ float dpp_add_qp1(float v) {   // lane^1
    float r;
    asm volatile("s_nop 1\n\tv_add_f32_dpp %0, %1, %1 quad_perm:[1,0,3,2] row_mask:0xf bank_mask:0xf"
                 : "=v"(r) : "v"(v));
    return r;
}
__device__ __forceinline__ float dpp_add_qp2(float v) {   // lane^2
    float r;
    asm volatile("s_nop 1\n\tv_add_f32_dpp %0, %1, %1 quad_perm:[2,3,0,1] row_mask:0xf bank_mask:0xf"
                 : "=v"(r) : "v"(v));
    return r;
}
__device__ __forceinline__ float dpp_add_hm(float v) {    // lane^7
    float r;
    asm volatile("s_nop 1\n\tv_add_f32_dpp %0, %1, %1 row_half_mirror row_mask:0xf bank_mask:0xf"
                 : "=v"(r) : "v"(v));
    return r;
}
// truncation bf16 split: x ~= hi + lo, |err| ~ 2^-16 rel
__device__ __forceinline__ void bfsplit(float x, short& hi, short& lo) {
    unsigned u = __float_as_uint(x);
    unsigned short h = (unsigned short)(u >> 16);
    float fh = __uint_as_float(((unsigned)h) << 16);
    float r  = x - fh;
    hi = (short)h;
    lo = (short)(__float_as_uint(r) >> 16);
}

__launch_bounds__(128, 1)
__global__ void mono_lstm_kernel(const float* __restrict__ x,
                                 const float* __restrict__ z0,
                                 const float* __restrict__ W_ih,
                                 const float* __restrict__ W_hh,
                                 const float* __restrict__ b_ih,
                                 const float* __restrict__ b_hh,
                                 const float* __restrict__ W1,
                                 const float* __restrict__ b1,
                                 const float* __restrict__ W2,
                                 const float* __restrict__ b2,
                                 float* __restrict__ out) {
    __shared__ float pls[2 * NB * PSTR];   // P double buffer
    __shared__ float zls[NB * ZSTR];       // z output buffer

    const int tid  = threadIdx.x;
    const int lane = tid & 63;
    const int wv   = tid >> 6;
    // role flip: co-resident blocks (i, i+256) get different consumer
    // wave-slots -> consumers can't share a SIMD if placement is wv%4-based
    const int flip = (blockIdx.x >> 8) & 1;
    const int role = wv ^ flip;           // 0 = consumer, 1 = producer
    const int bl   = lane >> 3;           // local batch 0..7
    const int j    = lane & 7;            // hidden unit owned by this lane
    const int bg   = blockIdx.x * NB;

    const float L2E = 1.4426950408889634f;
    const float NSC = -L2E;               // i,f,o scale (negated for exp2(-u))
    const float NSG = -2.0f * L2E;        // g scale; also KC = cell scale
    const float CPK =  2.0f * L2E;        // -KC

    // ================= producer state =================
    const int n  = lane & 15;             // MFMA N index
    const int kq = lane >> 4;
    bf16x8 Bh0, Bl0, Bh1, Bl1;
    float bias0 = 0.f, bias1 = 0.f;

    const int   am  = lane & 15;
    const float* xa = x + ((size_t)(bg + (am >> 1)) * T_LEN + (am & 1)) * F_IN + kq * 8;

    // gate-interleaved P dword slots: unit u holds (i,f,g,o) at 4u..4u+3
    const int p0 = (n < 8) ? 4 * n : 4 * (n - 8) + 1;
    const int p1 = (n < 8) ? 4 * n + 2 : 4 * (n - 8) + 3;

    float4 rgv[8];
    auto load_x = [&](int ch) {   // x for chunk ch -> registers
#pragma unroll
        for (int s = 0; s < 4; ++s) {
            const float* p = xa + (size_t)(ch * TC + 2 * s) * F_IN;
            rgv[2 * s]     = *(const float4*)p;
            rgv[2 * s + 1] = *(const float4*)(p + 4);
        }
    };
    auto mfma_phase = [&](int buf) {  // P(chunk) from rgv -> pls[buf]
#pragma unroll
        for (int s = 0; s < 4; ++s) {
            const float xv[8] = {rgv[2*s].x, rgv[2*s].y, rgv[2*s].z, rgv[2*s].w,
                                 rgv[2*s+1].x, rgv[2*s+1].y, rgv[2*s+1].z, rgv[2*s+1].w};
            bf16x8 Ah, Al;
#pragma unroll
            for (int i = 0; i < 8; ++i) {
                short h, l;
                bfsplit(xv[i], h, l);
                Ah[i] = h; Al[i] = l;
            }
            floatx4 a0 = {bias0, bias0, bias0, bias0};
            floatx4 a1 = {bias1, bias1, bias1, bias1};
            a0 = __builtin_amdgcn_mfma_f32_16x16x32_bf16(Ah, Bh0, a0, 0, 0, 0);
            a0 = __builtin_amdgcn_mfma_f32_16x16x32_bf16(Al, Bh0, a0, 0, 0, 0);
            a0 = __builtin_amdgcn_mfma_f32_16x16x32_bf16(Ah, Bl0, a0, 0, 0, 0);
            a1 = __builtin_amdgcn_mfma_f32_16x16x32_bf16(Ah, Bh1, a1, 0, 0, 0);
            a1 = __builtin_amdgcn_mfma_f32_16x16x32_bf16(Al, Bh1, a1, 0, 0, 0);
            a1 = __builtin_amdgcn_mfma_f32_16x16x32_bf16(Ah, Bl1, a1, 0, 0, 0);
#pragma unroll
            for (int reg = 0; reg < 4; ++reg) {
                const int mr = (lane >> 4) * 4 + reg;      // C/D row = A m-row
                const int bb = mr >> 1, tt = 2 * s + (mr & 1);
                pls[buf * NB * PSTR + bb * PSTR + tt * 32 + p0] = a0[reg];
                pls[buf * NB * PSTR + bb * PSTR + tt * 32 + p1] = a1[reg];
            }
        }
    };

    // ================= consumer state =================
    floatx2 wif[8], wgo[8];               // packed recurrence weights (i,f)/(g,o)
    floatx2 wzif = {0.f, 0.f}, wzgo = {0.f, 0.f};
    float w1own[8];                       // W1 row j (xor-permuted), 0 for j>=5
    float b1own = 0.f, w2own = 0.f, b2l = 0.f;
    float ha0 = 0.f, ha1 = 0.f, ha2 = 0.f, ha3 = 0.f,
          ha4 = 0.f, ha5 = 0.f, ha6 = 0.f, ha7 = 0.f;   // h_{j^k}
    float ck = 0.0f;                      // scaled cell: c * (-2*log2e)
    float z = 0.f;
    float zk = 0.f;                       // z kept at t == j (per chunk)
#pragma unroll
    for (int k = 0; k < 8; ++k) { w1own[k] = 0.f; wif[k] = (floatx2){0.f, 0.f}; wgo[k] = (floatx2){0.f, 0.f}; }

    if (role == 1) {
        // ---- MFMA B fragments: N-tile0 rows 0..15 (i,f), tile1 rows 16..31 (g,o)
        const int row0 = n, row1 = 16 + n;
        const float sc0 = NSC;
        const float sc1 = (n < 8) ? NSG : NSC;
#pragma unroll
        for (int i = 0; i < 8; ++i) {
            const int k = kq * 8 + i;
            short h, l;
            bfsplit(W_ih[row0 * 33 + k] * sc0, h, l); Bh0[i] = h; Bl0[i] = l;
            bfsplit(W_ih[row1 * 33 + k] * sc1, h, l); Bh1[i] = h; Bl1[i] = l;
        }
        bias0 = (b_ih[row0] + b_hh[row0]) * sc0;
        bias1 = (b_ih[row1] + b_hh[row1]) * sc1;

        load_x(0);
        mfma_phase(0);
        load_x(1);
    } else {
        // ---- recurrence weights (per lane, xor-gather order, packed pairs) ----
        const int ri = j, rf = 8 + j, rg_ = 16 + j, ro = 24 + j;
#pragma unroll
        for (int k = 0; k < 8; ++k) {
            wif[k] = (floatx2){W_hh[ri * 8 + (j ^ k)] * NSC,
                               W_hh[rf * 8 + (j ^ k)] * NSC};
            wgo[k] = (floatx2){W_hh[rg_ * 8 + (j ^ k)] * NSG,
                               W_hh[ro * 8 + (j ^ k)] * NSC};
        }
        wzif = (floatx2){W_ih[ri * 33 + 32] * NSC, W_ih[rf * 33 + 32] * NSC};
        wzgo = (floatx2){W_ih[rg_ * 33 + 32] * NSG, W_ih[ro * 33 + 32] * NSC};

        // ---- head: lane j owns head unit j (j<5), others zero ----
        if (j < 5) {
#pragma unroll
            for (int k = 0; k < 8; ++k) w1own[k] = W1[j * 8 + (j ^ k)];
            b1own = b1[j];
            w2own = W2[j];
        }
        b2l = (j == 0) ? b2[0] : 0.f;     // b2 folded into lane-0's e
        z = z0[bg + bl];
    }

    __syncthreads();   // P(0) ready

    for (int ch = 0; ch < NCH; ++ch) {
        if (role == 1) {
            // producer: P(ch+1) into the other buffer while consumer eats P(ch)
            if (ch + 1 < NCH) {
                mfma_phase((ch + 1) & 1);
                if (ch + 2 < NCH) load_x(ch + 2);
            }
        } else {
            // consumer: prefetch this chunk's P (8 x ds_read_b128, off-chain)
            const int base = (ch & 1) * NB * PSTR + bl * PSTR;
            float4 pq[TC];
#pragma unroll
            for (int t = 0; t < TC; ++t)
                pq[t] = *(const float4*)&pls[base + t * 32 + 4 * j];

#pragma unroll
            for (int t = 0; t < TC; ++t) {
                const floatx2 z2  = {z, z};
                const floatx2 hb0 = {ha0, ha0}, hb1 = {ha1, ha1},
                              hb2 = {ha2, ha2}, hb3 = {ha3, ha3},
                              hb4 = {ha4, ha4}, hb5 = {ha5, ha5},
                              hb6 = {ha6, ha6}, hb7 = {ha7, ha7};
                const floatx2 pIF = {pq[t].x, pq[t].y};
                const floatx2 pGO = {pq[t].z, pq[t].w};

                // serial pk-fma matvec (8 fma deep, on the slack ha-path);
                // z enters LAST so the z->a link stays 1
                floatx2 acIF = wif[7]*hb7 + pIF;
                acIF = wif[6]*hb6 + acIF;  acIF = wif[5]*hb5 + acIF;
                acIF = wif[4]*hb4 + acIF;  acIF = wif[3]*hb3 + acIF;
                acIF = wif[2]*hb2 + acIF;  acIF = wif[1]*hb1 + acIF;
                acIF = wif[0]*hb0 + acIF;
                const floatx2 aIF = wzif*z2 + acIF;
                floatx2 acGO = wgo[7]*hb7 + pGO;
                acGO = wgo[6]*hb6 + acGO;  acGO = wgo[5]*hb5 + acGO;
                acGO = wgo[4]*hb4 + acGO;  acGO = wgo[3]*hb3 + acGO;
                acGO = wgo[2]*hb2 + acGO;  acGO = wgo[1]*hb1 + acGO;
                acGO = wgo[0]*hb0 + acGO;
                const floatx2 aGO = wzgo*z2 + acGO;

                const float eI = EX2(aIF.x), eF = EX2(aIF.y);
                const float eG = EX2(aGO.x), eO = EX2(aGO.y);

                // si*tanh(g) via single rcp; scaled cell ck = c*KC, KC=-2log2e
                const float sf  = RCP(1.0f + eF);
                const float so  = RCP(1.0f + eO);
                const float den = (1.0f + eI) * (1.0f + eG);
                const float r   = RCP(den);
                const float numK = fmaf(CPK, eG, NSG);   // KC*(1-eG)
                const float sitgK = r * numK;
                ck = fmaf(sf, ck, sitgK);                // ck = KC*c
                const float ec  = EX2(ck);               // e^{-2c}
                const float rc  = RCP(1.0f + ec);
                const float so2 = so + so;
                const float hn  = fmaf(so2, rc, -so);    // so*tanh(c)

                // gather h_{j^k}: pure DPP within the 8-lane group, depth 2
                ha0 = hn;
                ha1 = dppf<QP(1, 0, 3, 2)>(hn);
                ha2 = dppf<QP(2, 3, 0, 1)>(hn);
                ha3 = dppf<QP(3, 2, 1, 0)>(hn);
                const float t7 = dppf<DPP_HM>(hn);
                ha7 = t7;
                ha4 = dppf<QP(3, 2, 1, 0)>(t7);
                ha5 = dppf<QP(2, 3, 0, 1)>(t7);
                ha6 = dppf<QP(1, 0, 3, 2)>(t7);

                // head: distributed (lane j = unit j); b2 folded into lane 0
                float da = fmaf(w1own[2], ha2, fmaf(w1own[1], ha1,
                           fmaf(w1own[0], ha0, b1own)));
                float db = fmaf(w1own[5], ha5, fmaf(w1own[4], ha4, w1own[3] * ha3));
                float dc = fmaf(w1own[7], ha7, w1own[6] * ha6);
                const float d = fmaxf((da + db) + dc, 0.0f);
                const float e = fmaf(w2own, d, b2l);     // w2own=0 for j>=5

                // fused butterfly sum (xor basis {1,2,7}): 3 instructions
                float q = dpp_add_qp1(e);
                q = dpp_add_qp2(q);
                q = dpp_add_hm(q);

                z += fmaxf(q, 0.0f);
                zk = (j == t) ? z : zk;   // cndmask keep, no exec churn
            }
            // chunk-end z store: lane j writes its kept t = ch*8 + j
            zls[bl * ZSTR + ch * TC + j] = zk;
        }
        __syncthreads();   // P(ch+1) ready; buf[ch&1] free for producer
    }

    // coalesced output store, both waves (zls visible via loop's final barrier)
#pragma unroll
    for (int it = 0; it < 4; ++it) {
        const int idx = tid + it * 128;          // float4 index, NB*50 = 400 total
        if (idx < NB * (T_LEN / 4)) {
            const int bb = idx / 50, rem = idx - bb * 50;
            *(float4*)&out[(size_t)(bg + bb) * T_LEN + rem * 4] =
                *(const float4*)&zls[bb * ZSTR + rem * 4];
        }
    }
}

extern "C" void kernel_launch(void* const* d_in, const int* in_sizes, int n_in,
                              void* d_out, int out_size, void* d_ws, size_t ws_size,
                              hipStream_t stream) {
    const float* x    = (const float*)d_in[0];
    const float* z0   = (const float*)d_in[1];
    const float* W_ih = (const float*)d_in[2];
    const float* W_hh = (const float*)d_in[3];
    const float* b_ih = (const float*)d_in[4];
    const float* b_hh = (const float*)d_in[5];
    const float* W1   = (const float*)d_in[6];
    const float* b1   = (const float*)d_in[7];
    const float* W2   = (const float*)d_in[8];
    const float* b2   = (const float*)d_in[9];
    float* out = (float*)d_out;

    const int B = in_sizes[1];
    dim3 grid(B / NB), block(128);
    hipLaunchKernelGGL(mono_lstm_kernel, grid, block, 0, stream,
                       x, z0, W_ih, W_hh, b_ih, b_hh, W1, b1, W2, b2, out);
}

// Round 9
// 173.881 us; speedup vs baseline: 1.0054x; 1.0054x over previous
//
#include <hip/hip_runtime.h>

#define T_LEN 200
#define F_IN  32
#define TC    8                 // timesteps per chunk; 200 = 25 * 8
#define NCH   (T_LEN / TC)
#define NB    8                 // batches per block
#define PSTR  264               // P stride per batch (dwords), 16B-aligned
#define ZSTR  204               // z stride per batch (dwords), 16B-aligned rows

#define QP(a,b,c,d) ((a)|((b)<<2)|((c)<<4)|((d)<<6))
#define DPP_HM 0x141            // row_half_mirror: lane^7 within each 8-group
#define EX2(v) __builtin_amdgcn_exp2f(v)
#define RCP(v) __builtin_amdgcn_rcpf(v)

typedef short  bf16x8  __attribute__((ext_vector_type(8)));
typedef float  floatx4 __attribute__((ext_vector_type(4)));
typedef float  floatx2 __attribute__((ext_vector_type(2)));

template <int CTRL>
__device__ __forceinline__ float dppf(float v) {
    return __int_as_float(__builtin_amdgcn_update_dpp(
        0, __float_as_int(v), CTRL, 0xF, 0xF, true));
}
// fused butterfly stages: dst = dpp(src) + src, one VALU instr each
// (s_nop 1 guards the VALU-write -> DPP-read hazard)
__device__ __forceinline__ float dpp_add_qp1(float v) {   // lane^1
    float r;
    asm volatile("s_nop 1\n\tv_add_f32_dpp %0, %1, %1 quad_perm:[1,0,3,2] row_mask:0xf bank_mask:0xf"
                 : "=v"(r) : "v"(v));
    return r;
}
__device__ __forceinline__ float dpp_add_qp2(float v) {   // lane^2
    float r;
    asm volatile("s_nop 1\n\tv_add_f32_dpp %0, %1, %1 quad_perm:[2,3,0,1] row_mask:0xf bank_mask:0xf"
                 : "=v"(r) : "v"(v));
    return r;
}
__device__ __forceinline__ float dpp_add_hm(float v) {    // lane^7
    float r;
    asm volatile("s_nop 1\n\tv_add_f32_dpp %0, %1, %1 row_half_mirror row_mask:0xf bank_mask:0xf"
                 : "=v"(r) : "v"(v));
    return r;
}
// truncation bf16 split: x ~= hi + lo, |err| ~ 2^-16 rel
__device__ __forceinline__ void bfsplit(float x, short& hi, short& lo) {
    unsigned u = __float_as_uint(x);
    unsigned short h = (unsigned short)(u >> 16);
    float fh = __uint_as_float(((unsigned)h) << 16);
    float r  = x - fh;
    hi = (short)h;
    lo = (short)(__float_as_uint(r) >> 16);
}

__launch_bounds__(128, 1)
__global__ void mono_lstm_kernel(const float* __restrict__ x,
                                 const float* __restrict__ z0,
                                 const float* __restrict__ W_ih,
                                 const float* __restrict__ W_hh,
                                 const float* __restrict__ b_ih,
                                 const float* __restrict__ b_hh,
                                 const float* __restrict__ W1,
                                 const float* __restrict__ b1,
                                 const float* __restrict__ W2,
                                 const float* __restrict__ b2,
                                 float* __restrict__ out) {
    __shared__ float pls[2 * NB * PSTR];   // P double buffer
    __shared__ float zls[NB * ZSTR];       // z output buffer

    const int tid  = threadIdx.x;
    const int lane = tid & 63;
    const int wv   = tid >> 6;
    const int role = wv;                  // 0 = consumer, 1 = producer
    const int bl   = lane >> 3;           // local batch 0..7
    const int j    = lane & 7;            // hidden unit owned by this lane
    const int bg   = blockIdx.x * NB;

    const float L2E = 1.4426950408889634f;
    const float NSC = -L2E;               // i,f,o scale (negated for exp2(-u))
    const float NSG = -2.0f * L2E;        // g scale; also KC = cell scale
    const float CPK =  2.0f * L2E;        // -KC

    // ================= producer state =================
    const int n  = lane & 15;             // MFMA N index
    const int kq = lane >> 4;
    bf16x8 Bh0, Bl0, Bh1, Bl1;
    float bias0 = 0.f, bias1 = 0.f;

    const int   am  = lane & 15;
    const float* xa = x + ((size_t)(bg + (am >> 1)) * T_LEN + (am & 1)) * F_IN + kq * 8;

    // gate-interleaved P dword slots: unit u holds (i,f,g,o) at 4u..4u+3
    const int p0 = (n < 8) ? 4 * n : 4 * (n - 8) + 1;
    const int p1 = (n < 8) ? 4 * n + 2 : 4 * (n - 8) + 3;

    float4 rgv[8];
    auto load_x = [&](int ch) {   // x for chunk ch -> registers
#pragma unroll
        for (int s = 0; s < 4; ++s) {
            const float* p = xa + (size_t)(ch * TC + 2 * s) * F_IN;
            rgv[2 * s]     = *(const float4*)p;
            rgv[2 * s + 1] = *(const float4*)(p + 4);
        }
    };
    auto mfma_phase = [&](int buf) {  // P(chunk) from rgv -> pls[buf]
#pragma unroll
        for (int s = 0; s < 4; ++s) {
            const float xv[8] = {rgv[2*s].x, rgv[2*s].y, rgv[2*s].z, rgv[2*s].w,
                                 rgv[2*s+1].x, rgv[2*s+1].y, rgv[2*s+1].z, rgv[2*s+1].w};
            bf16x8 Ah, Al;
#pragma unroll
            for (int i = 0; i < 8; ++i) {
                short h, l;
                bfsplit(xv[i], h, l);
                Ah[i] = h; Al[i] = l;
            }
            floatx4 a0 = {bias0, bias0, bias0, bias0};
            floatx4 a1 = {bias1, bias1, bias1, bias1};
            a0 = __builtin_amdgcn_mfma_f32_16x16x32_bf16(Ah, Bh0, a0, 0, 0, 0);
            a0 = __builtin_amdgcn_mfma_f32_16x16x32_bf16(Al, Bh0, a0, 0, 0, 0);
            a0 = __builtin_amdgcn_mfma_f32_16x16x32_bf16(Ah, Bl0, a0, 0, 0, 0);
            a1 = __builtin_amdgcn_mfma_f32_16x16x32_bf16(Ah, Bh1, a1, 0, 0, 0);
            a1 = __builtin_amdgcn_mfma_f32_16x16x32_bf16(Al, Bh1, a1, 0, 0, 0);
            a1 = __builtin_amdgcn_mfma_f32_16x16x32_bf16(Ah, Bl1, a1, 0, 0, 0);
#pragma unroll
            for (int reg = 0; reg < 4; ++reg) {
                const int mr = (lane >> 4) * 4 + reg;      // C/D row = A m-row
                const int bb = mr >> 1, tt = 2 * s + (mr & 1);
                pls[buf * NB * PSTR + bb * PSTR + tt * 32 + p0] = a0[reg];
                pls[buf * NB * PSTR + bb * PSTR + tt * 32 + p1] = a1[reg];
            }
        }
    };

    // ================= consumer state =================
    floatx2 wif[8], wgo[8];               // packed recurrence weights (i,f)/(g,o)
    floatx2 wzif = {0.f, 0.f}, wzgo = {0.f, 0.f};
    float w1own[8];                       // W1 row j (xor-permuted), 0 for j>=5
    float b1own = 0.f, w2own = 0.f, b2l = 0.f;
    float ha0 = 0.f, ha1 = 0.f, ha2 = 0.f, ha3 = 0.f,
          ha4 = 0.f, ha5 = 0.f, ha6 = 0.f, ha7 = 0.f;   // h_{j^k}
    float ck = 0.0f;                      // scaled cell: c * (-2*log2e)
    float z = 0.f;
    float zk = 0.f;                       // z kept at t == j (per chunk)
#pragma unroll
    for (int k = 0; k < 8; ++k) { w1own[k] = 0.f; wif[k] = (floatx2){0.f, 0.f}; wgo[k] = (floatx2){0.f, 0.f}; }

    if (role == 1) {
        // ---- MFMA B fragments: N-tile0 rows 0..15 (i,f), tile1 rows 16..31 (g,o)
        const int row0 = n, row1 = 16 + n;
        const float sc0 = NSC;
        const float sc1 = (n < 8) ? NSG : NSC;
#pragma unroll
        for (int i = 0; i < 8; ++i) {
            const int k = kq * 8 + i;
            short h, l;
            bfsplit(W_ih[row0 * 33 + k] * sc0, h, l); Bh0[i] = h; Bl0[i] = l;
            bfsplit(W_ih[row1 * 33 + k] * sc1, h, l); Bh1[i] = h; Bl1[i] = l;
        }
        bias0 = (b_ih[row0] + b_hh[row0]) * sc0;
        bias1 = (b_ih[row1] + b_hh[row1]) * sc1;

        load_x(0);
        mfma_phase(0);
        load_x(1);
    } else {
        // ---- recurrence weights (per lane, xor-gather order, packed pairs) ----
        const int ri = j, rf = 8 + j, rg_ = 16 + j, ro = 24 + j;
#pragma unroll
        for (int k = 0; k < 8; ++k) {
            wif[k] = (floatx2){W_hh[ri * 8 + (j ^ k)] * NSC,
                               W_hh[rf * 8 + (j ^ k)] * NSC};
            wgo[k] = (floatx2){W_hh[rg_ * 8 + (j ^ k)] * NSG,
                               W_hh[ro * 8 + (j ^ k)] * NSC};
        }
        wzif = (floatx2){W_ih[ri * 33 + 32] * NSC, W_ih[rf * 33 + 32] * NSC};
        wzgo = (floatx2){W_ih[rg_ * 33 + 32] * NSG, W_ih[ro * 33 + 32] * NSC};

        // ---- head: lane j owns head unit j (j<5), others zero ----
        if (j < 5) {
#pragma unroll
            for (int k = 0; k < 8; ++k) w1own[k] = W1[j * 8 + (j ^ k)];
            b1own = b1[j];
            w2own = W2[j];
        }
        b2l = (j == 0) ? b2[0] : 0.f;     // b2 folded into lane-0's e
        z = z0[bg + bl];
    }

    __syncthreads();   // P(0) ready

    for (int ch = 0; ch < NCH; ++ch) {
        if (role == 1) {
            // producer: P(ch+1) into the other buffer while consumer eats P(ch)
            if (ch + 1 < NCH) {
                mfma_phase((ch + 1) & 1);
                if (ch + 2 < NCH) load_x(ch + 2);
            }
        } else {
            // consumer: prefetch this chunk's P (8 x ds_read_b128, off-chain)
            const int base = (ch & 1) * NB * PSTR + bl * PSTR;
            float4 pq[TC];
#pragma unroll
            for (int t = 0; t < TC; ++t)
                pq[t] = *(const float4*)&pls[base + t * 32 + 4 * j];

#pragma unroll
            for (int t = 0; t < TC; ++t) {
                const floatx2 z2  = {z, z};
                const floatx2 hb0 = {ha0, ha0}, hb1 = {ha1, ha1},
                              hb2 = {ha2, ha2}, hb3 = {ha3, ha3},
                              hb4 = {ha4, ha4}, hb5 = {ha5, ha5},
                              hb6 = {ha6, ha6}, hb7 = {ha7, ha7};
                const floatx2 pIF = {pq[t].x, pq[t].y};
                const floatx2 pGO = {pq[t].z, pq[t].w};

                // tree pk-fma matvec (depth 4 from ha-ready); z enters LAST
                floatx2 mIF = wif[0]*hb0 + (wif[1]*hb1 + (wif[2]*hb2 + (wif[3]*hb3 + pIF)));
                floatx2 nIF = wif[4]*hb4 + (wif[5]*hb5 + (wif[6]*hb6 + wif[7]*hb7));
                const floatx2 aIF = wzif*z2 + (mIF + nIF);
                floatx2 mGO = wgo[0]*hb0 + (wgo[1]*hb1 + (wgo[2]*hb2 + (wgo[3]*hb3 + pGO)));
                floatx2 nGO = wgo[4]*hb4 + (wgo[5]*hb5 + (wgo[6]*hb6 + wgo[7]*hb7));
                const floatx2 aGO = wzgo*z2 + (mGO + nGO);

                const float eI = EX2(aIF.x), eF = EX2(aIF.y);
                const float eG = EX2(aGO.x), eO = EX2(aGO.y);

                const float opI = 1.0f + eI, opF = 1.0f + eF;
                const float opG = 1.0f + eG, opO = 1.0f + eO;

                // merged cell update (single RCP):
                //   sf*ck + r*numK = (ck*deng + numK*opF) * RCP(deng*opF)
                const float deng = opI * opG;
                const float den3 = deng * opF;
                const float Rg   = RCP(den3);
                const float numK = fmaf(CPK, eG, NSG);   // KC*(1-eG)
                const float t1   = ck * deng;            // ck slack path
                const float t2   = numK * opF;
                ck = (t1 + t2) * Rg;                     // ck = KC*c

                // merged output (single RCP):
                //   hn = so*tanh(c) = (1-ec) * RCP((1+ec)*(1+eO))
                const float ec   = EX2(ck);              // e^{-2c}
                const float opC  = 1.0f + ec;
                const float numC = 1.0f - ec;
                const float Rh   = RCP(opC * opO);
                const float hn   = numC * Rh;

                // gather h_{j^k}: pure DPP within the 8-lane group, depth 2
                ha0 = hn;
                ha1 = dppf<QP(1, 0, 3, 2)>(hn);
                ha2 = dppf<QP(2, 3, 0, 1)>(hn);
                ha3 = dppf<QP(3, 2, 1, 0)>(hn);
                const float t7 = dppf<DPP_HM>(hn);
                ha7 = t7;
                ha4 = dppf<QP(3, 2, 1, 0)>(t7);
                ha5 = dppf<QP(2, 3, 0, 1)>(t7);
                ha6 = dppf<QP(1, 0, 3, 2)>(t7);

                // head: distributed (lane j = unit j); b2 folded into lane 0
                float da = fmaf(w1own[2], ha2, fmaf(w1own[1], ha1,
                           fmaf(w1own[0], ha0, b1own)));
                float db = fmaf(w1own[5], ha5, fmaf(w1own[4], ha4, w1own[3] * ha3));
                float dc = fmaf(w1own[7], ha7, w1own[6] * ha6);
                const float d = fmaxf((da + db) + dc, 0.0f);
                const float e = fmaf(w2own, d, b2l);     // w2own=0 for j>=5

                // fused butterfly sum (xor basis {1,2,7}): 3 instructions
                float q = dpp_add_qp1(e);
                q = dpp_add_qp2(q);
                q = dpp_add_hm(q);

                z += fmaxf(q, 0.0f);
                zk = (j == t) ? z : zk;   // cndmask keep, no exec churn
            }
            // chunk-end z store: lane j writes its kept t = ch*8 + j
            zls[bl * ZSTR + ch * TC + j] = zk;
        }
        __syncthreads();   // P(ch+1) ready; buf[ch&1] free for producer
    }

    // coalesced output store, both waves (zls visible via loop's final barrier)
#pragma unroll
    for (int it = 0; it < 4; ++it) {
        const int idx = tid + it * 128;          // float4 index, NB*50 = 400 total
        if (idx < NB * (T_LEN / 4)) {
            const int bb = idx / 50, rem = idx - bb * 50;
            *(float4*)&out[(size_t)(bg + bb) * T_LEN + rem * 4] =
                *(const float4*)&zls[bb * ZSTR + rem * 4];
        }
    }
}

extern "C" void kernel_launch(void* const* d_in, const int* in_sizes, int n_in,
                              void* d_out, int out_size, void* d_ws, size_t ws_size,
                              hipStream_t stream) {
    const float* x    = (const float*)d_in[0];
    const float* z0   = (const float*)d_in[1];
    const float* W_ih = (const float*)d_in[2];
    const float* W_hh = (const float*)d_in[3];
    const float* b_ih = (const float*)d_in[4];
    const float* b_hh = (const float*)d_in[5];
    const float* W1   = (const float*)d_in[6];
    const float* b1   = (const float*)d_in[7];
    const float* W2   = (const float*)d_in[8];
    const float* b2   = (const float*)d_in[9];
    float* out = (float*)d_out;

    const int B = in_sizes[1];
    dim3 grid(B / NB), block(128);
    hipLaunchKernelGGL(mono_lstm_kernel, grid, block, 0, stream,
                       x, z0, W_ih, W_hh, b_ih, b_hh, W1, b1, W2, b2, out);
}